// Round 1
// baseline (52714.008 us; speedup 1.0000x reference)
//
#include <hip/hip_runtime.h>
#include <hip/hip_bf16.h>
#include <math.h>

#define L_SEQ 4096
#define DM 512
#define DI 1024
#define DSTATE 16
#define NLAYERS 4

typedef __bf16 v8bf __attribute__((ext_vector_type(8)));
typedef __bf16 v4bf __attribute__((ext_vector_type(4)));
typedef float  v4f  __attribute__((ext_vector_type(4)));

static __device__ __forceinline__ v4f mfma16(v8bf a, v8bf b, v4f c) {
  return __builtin_amdgcn_mfma_f32_16x16x32_bf16(a, b, c, 0, 0, 0);
}

// ---------------------------------------------------------------------------
// Embed: h[m][d] = in_b[d] + sum_c x[b][c][l] * in_w[d][c]
// ---------------------------------------------------------------------------
__global__ void embed_kernel(const float* __restrict__ x, const float* __restrict__ in_w,
                             const float* __restrict__ in_b, float* __restrict__ h,
                             int b0, int Mc) {
  int idx = blockIdx.x * 256 + threadIdx.x;   // over Mc*512
  int d = idx & (DM - 1);
  int m = idx >> 9;
  if (m >= Mc) return;
  int bg = b0 + (m >> 12);
  int l  = m & (L_SEQ - 1);
  const float* xp = x + ((size_t)bg * 3) * L_SEQ + l;
  float v = in_b[d] + xp[0] * in_w[d*3+0] + xp[L_SEQ] * in_w[d*3+1] + xp[2*L_SEQ] * in_w[d*3+2];
  h[(size_t)m * DM + d] = v;
}

// ---------------------------------------------------------------------------
// Split-bf16 3-pass MFMA GEMM: C[M][N] = A[M][K] * B[N][K]^T  (all fp32 in/out)
// Tile BM=128 BN=64 BK=64, 256 threads (4 waves), wave -> 32 rows x 64 cols.
// LDS row layout: 8 kgroups * (8 bf16 hi | 8 bf16 lo) = 256B + 16B pad = 272B.
// ---------------------------------------------------------------------------
#define GBM 128
#define GBN 64
#define GBK 64
#define ROWB 272

__global__ __launch_bounds__(256) void gemm_split3(
    const float* __restrict__ A, const float* __restrict__ Bw, float* __restrict__ C,
    int M, int N, int K, int lda, int ldb, int ldc) {
  __shared__ __align__(16) char lds[GBM * ROWB + GBN * ROWB];
  char* aLds = lds;
  char* bLds = lds + GBM * ROWB;
  int tid  = threadIdx.x;
  int m0   = blockIdx.y * GBM;
  int n0   = blockIdx.x * GBN;
  int wave = tid >> 6, lane = tid & 63;
  int lrow = lane & 15, lq = lane >> 4;

  v4f acc[2][4];
#pragma unroll
  for (int i = 0; i < 2; ++i)
#pragma unroll
    for (int j = 0; j < 4; ++j)
#pragma unroll
      for (int e = 0; e < 4; ++e) acc[i][j][e] = 0.0f;

  int srow = tid >> 4;            // 0..15
  int scol = (tid & 15) * 4;      // float4 col within BK
  int kg   = scol >> 3;           // kgroup 0..7
  int ko   = scol & 7;            // 0 or 4

  for (int k0 = 0; k0 < K; k0 += GBK) {
    float4 av[8];
#pragma unroll
    for (int r = 0; r < 8; ++r)
      av[r] = *reinterpret_cast<const float4*>(A + (size_t)(m0 + srow + 16*r) * lda + k0 + scol);
    float4 bv[4];
#pragma unroll
    for (int r = 0; r < 4; ++r)
      bv[r] = *reinterpret_cast<const float4*>(Bw + (size_t)(n0 + srow + 16*r) * ldb + k0 + scol);

    __syncthreads();
#pragma unroll
    for (int r = 0; r < 8; ++r) {
      float4 v = av[r];
      char* p = aLds + (srow + 16*r) * ROWB + kg * 32 + ko * 2;
      v4bf hv, lv;
      hv[0]=(__bf16)v.x; hv[1]=(__bf16)v.y; hv[2]=(__bf16)v.z; hv[3]=(__bf16)v.w;
      lv[0]=(__bf16)(v.x-(float)hv[0]); lv[1]=(__bf16)(v.y-(float)hv[1]);
      lv[2]=(__bf16)(v.z-(float)hv[2]); lv[3]=(__bf16)(v.w-(float)hv[3]);
      *reinterpret_cast<v4bf*>(p)      = hv;
      *reinterpret_cast<v4bf*>(p + 16) = lv;
    }
#pragma unroll
    for (int r = 0; r < 4; ++r) {
      float4 v = bv[r];
      char* p = bLds + (srow + 16*r) * ROWB + kg * 32 + ko * 2;
      v4bf hv, lv;
      hv[0]=(__bf16)v.x; hv[1]=(__bf16)v.y; hv[2]=(__bf16)v.z; hv[3]=(__bf16)v.w;
      lv[0]=(__bf16)(v.x-(float)hv[0]); lv[1]=(__bf16)(v.y-(float)hv[1]);
      lv[2]=(__bf16)(v.z-(float)hv[2]); lv[3]=(__bf16)(v.w-(float)hv[3]);
      *reinterpret_cast<v4bf*>(p)      = hv;
      *reinterpret_cast<v4bf*>(p + 16) = lv;
    }
    __syncthreads();

#pragma unroll
    for (int kk = 0; kk < GBK / 32; ++kk) {
      v8bf aF[2][2], bF[4][2];
#pragma unroll
      for (int mt = 0; mt < 2; ++mt) {
        const char* p = aLds + (wave*32 + mt*16 + lrow) * ROWB + (kk*4 + lq) * 32;
        aF[mt][0] = *reinterpret_cast<const v8bf*>(p);
        aF[mt][1] = *reinterpret_cast<const v8bf*>(p + 16);
      }
#pragma unroll
      for (int nt = 0; nt < 4; ++nt) {
        const char* p = bLds + (nt*16 + lrow) * ROWB + (kk*4 + lq) * 32;
        bF[nt][0] = *reinterpret_cast<const v8bf*>(p);
        bF[nt][1] = *reinterpret_cast<const v8bf*>(p + 16);
      }
#pragma unroll
      for (int mt = 0; mt < 2; ++mt)
#pragma unroll
        for (int nt = 0; nt < 4; ++nt) {
          acc[mt][nt] = mfma16(aF[mt][0], bF[nt][0], acc[mt][nt]);  // hi*hi
          acc[mt][nt] = mfma16(aF[mt][0], bF[nt][1], acc[mt][nt]);  // hi*lo
          acc[mt][nt] = mfma16(aF[mt][1], bF[nt][0], acc[mt][nt]);  // lo*hi
        }
    }
  }

  // Epilogue: C/D layout col=lane&15, row=(lane>>4)*4+reg  [m89/m91-verified]
#pragma unroll
  for (int mt = 0; mt < 2; ++mt)
#pragma unroll
    for (int nt = 0; nt < 4; ++nt) {
      int rbase = m0 + wave*32 + mt*16 + lq*4;
      int cidx  = n0 + nt*16 + lrow;
#pragma unroll
      for (int r = 0; r < 4; ++r)
        C[(size_t)(rbase + r) * ldc + cidx] = acc[mt][nt][r];
    }
}

// ---------------------------------------------------------------------------
// Depthwise causal conv (k=4) + bias + SiLU.  xc = first half of xz rows.
// ---------------------------------------------------------------------------
__global__ void conv_silu_kernel(const float* __restrict__ xz, const float* __restrict__ cw,
                                 const float* __restrict__ cb, float* __restrict__ u, int Mc) {
  int idx = blockIdx.x * 256 + threadIdx.x;   // over Mc*DI
  int d = idx & (DI - 1);
  int m = idx >> 10;
  if (m >= Mc) return;
  int t = m & (L_SEQ - 1);
  float acc = cb[d];
#pragma unroll
  for (int k = 0; k < 4; ++k) {
    int tt = t - 3 + k;
    if (tt >= 0) acc += xz[(size_t)(m + k - 3) * 2048 + d] * cw[d*4 + k];
  }
  u[(size_t)m * DI + d] = acc / (1.0f + expf(-acc));
}

// ---------------------------------------------------------------------------
// dt[m][d] = softplus( dbl[m][0:32] . dtw[d][0:32] + dtb[d] )
// block: 256 d-lanes x 64 tokens; dtw tile staged in LDS (pad 33 -> conflict-free)
// ---------------------------------------------------------------------------
__global__ __launch_bounds__(256) void dt_kernel(const float* __restrict__ dbl,
                                                 const float* __restrict__ dtw,
                                                 const float* __restrict__ dtb,
                                                 float* __restrict__ dt, int Mc) {
  __shared__ float w[256][33];
  __shared__ float r32[32];
  int tid = threadIdx.x;
  int d0  = blockIdx.y * 256;
  int m0  = blockIdx.x * 64;
  for (int i = tid; i < 256 * 32; i += 256) {
    int rr = i >> 5, cc = i & 31;
    w[rr][cc] = dtw[(size_t)(d0 + rr) * 32 + cc];
  }
  float bias = dtb[d0 + tid];
  __syncthreads();
  for (int mi = 0; mi < 64; ++mi) {
    int m = m0 + mi;
    if (tid < 32) r32[tid] = dbl[(size_t)m * 64 + tid];
    __syncthreads();
    float acc = bias;
#pragma unroll
    for (int r = 0; r < 32; ++r) acc += r32[r] * w[tid][r];
    float o = (acc > 15.0f) ? acc : log1pf(expf(acc));
    dt[(size_t)m * DI + d0 + tid] = o;
    __syncthreads();
  }
}

// ---------------------------------------------------------------------------
// Selective scan + gate.  4 lanes per (b,d), 4 states each.
// LDS-tiled 16 timesteps.  y = (scan_y + u*Dp) * silu(z)
// ---------------------------------------------------------------------------
#define TT 16
__global__ __launch_bounds__(256) void scan_kernel(
    const float* __restrict__ dt, const float* __restrict__ u,
    const float* __restrict__ xz, const float* __restrict__ dbl,
    const float* __restrict__ Alog, const float* __restrict__ Dp,
    float* __restrict__ y) {
  __shared__ __align__(16) float s_dt[TT][64];
  __shared__ __align__(16) float s_u [TT][64];
  __shared__ __align__(16) float s_z [TT][64];
  __shared__ __align__(16) float s_bc[TT][32];
  __shared__ __align__(16) float s_y [TT][64];
  int tid = threadIdx.x;
  int bi  = blockIdx.x >> 4;            // chunk-local b
  int d0  = (blockIdx.x & 15) * 64;
  int dl  = tid >> 2;                   // 0..63
  int sg  = (tid & 3) * 4;              // state-group base
  int d   = d0 + dl;
  float a2[4], hst[4] = {0.f, 0.f, 0.f, 0.f};
#pragma unroll
  for (int j = 0; j < 4; ++j)
    a2[j] = -expf(Alog[(size_t)d * DSTATE + sg + j]) * 1.44269504088896340736f;
  float dp = Dp[d];
  size_t mbase = (size_t)bi * L_SEQ;

  int tr = tid >> 4;          // 0..15
  int c4 = (tid & 15) * 4;
  int tr2 = tid >> 3;         // for bc tile (first 128 threads)
  int c2  = (tid & 7) * 4;

  for (int t0 = 0; t0 < L_SEQ; t0 += TT) {
    size_t m = mbase + t0 + tr;
    *reinterpret_cast<float4*>(&s_dt[tr][c4]) = *reinterpret_cast<const float4*>(dt + m*DI + d0 + c4);
    *reinterpret_cast<float4*>(&s_u [tr][c4]) = *reinterpret_cast<const float4*>(u  + m*DI + d0 + c4);
    *reinterpret_cast<float4*>(&s_z [tr][c4]) = *reinterpret_cast<const float4*>(xz + m*2048 + DI + d0 + c4);
    if (tid < 128) {
      size_t m2 = mbase + t0 + tr2;
      *reinterpret_cast<float4*>(&s_bc[tr2][c2]) = *reinterpret_cast<const float4*>(dbl + m2*64 + 32 + c2);
    }
    __syncthreads();
#pragma unroll
    for (int t = 0; t < TT; ++t) {
      float dtv = s_dt[t][dl];
      float uv  = s_u[t][dl];
      float cu  = dtv * uv;
      float4 Bv = *reinterpret_cast<const float4*>(&s_bc[t][sg]);
      float4 Cv = *reinterpret_cast<const float4*>(&s_bc[t][16 + sg]);
      float yp = 0.0f;
      {
        float dA;
        dA = exp2f(dtv * a2[0]); hst[0] = dA*hst[0] + cu*Bv.x; yp += hst[0]*Cv.x;
        dA = exp2f(dtv * a2[1]); hst[1] = dA*hst[1] + cu*Bv.y; yp += hst[1]*Cv.y;
        dA = exp2f(dtv * a2[2]); hst[2] = dA*hst[2] + cu*Bv.z; yp += hst[2]*Cv.z;
        dA = exp2f(dtv * a2[3]); hst[3] = dA*hst[3] + cu*Bv.w; yp += hst[3]*Cv.w;
      }
      yp += __shfl_xor(yp, 1);
      yp += __shfl_xor(yp, 2);
      if ((tid & 3) == 0) {
        float zv = s_z[t][dl];
        s_y[t][dl] = (yp + uv * dp) * (zv / (1.0f + expf(-zv)));
      }
    }
    __syncthreads();
    *reinterpret_cast<float4*>(y + m*DI + d0 + c4) = *reinterpret_cast<float4*>(&s_y[tr][c4]);
    __syncthreads();
  }
}

// ---------------------------------------------------------------------------
// Pool: pooled[b][d] += mean-partial over 128 tokens
// ---------------------------------------------------------------------------
__global__ __launch_bounds__(512) void pool_kernel(const float* __restrict__ h,
                                                   float* __restrict__ pooled,
                                                   int b0) {
  int b = blockIdx.x >> 5;
  int chunk = blockIdx.x & 31;
  int d = threadIdx.x;
  float s = 0.0f;
  size_t base = (size_t)b * L_SEQ + chunk * 128;
  for (int l = 0; l < 128; ++l) s += h[(base + l) * DM + d];
  atomicAdd(pooled + (size_t)(b0 + b) * DM + d, s * (1.0f / 4096.0f));
}

// ---------------------------------------------------------------------------
// Head: LayerNorm over 512 + classifier (10 classes)
// ---------------------------------------------------------------------------
__global__ __launch_bounds__(512) void head_kernel(const float* __restrict__ pooled,
                                                   const float* __restrict__ nw,
                                                   const float* __restrict__ nbv,
                                                   const float* __restrict__ clw,
                                                   const float* __restrict__ clb,
                                                   float* __restrict__ out) {
  __shared__ float rs[8], rq[8];
  __shared__ float ln[512];
  int b = blockIdx.x, tid = threadIdx.x;
  int wid = tid >> 6, lane = tid & 63;
  float v = pooled[(size_t)b * DM + tid];
  float s = v, q = v * v;
#pragma unroll
  for (int off = 1; off < 64; off <<= 1) { s += __shfl_xor(s, off); q += __shfl_xor(q, off); }
  if (lane == 0) { rs[wid] = s; rq[wid] = q; }
  __syncthreads();
  if (tid == 0) {
    float S = 0, Q = 0;
    for (int i = 0; i < 8; ++i) { S += rs[i]; Q += rq[i]; }
    rs[0] = S; rq[0] = Q;
  }
  __syncthreads();
  float mu  = rs[0] / 512.0f;
  float var = rq[0] / 512.0f - mu * mu;
  ln[tid] = (v - mu) * rsqrtf(var + 1e-5f) * nw[tid] + nbv[tid];
  __syncthreads();
  if (tid < 320) {
    int c = tid >> 5, l2 = tid & 31;
    float p = 0.0f;
    for (int dd = l2; dd < 512; dd += 32) p += ln[dd] * clw[c * 512 + dd];
#pragma unroll
    for (int off = 1; off < 32; off <<= 1) p += __shfl_xor(p, off);
    if (l2 == 0) out[(size_t)b * 10 + c] = p + clb[c];
  }
}

// ---------------------------------------------------------------------------
extern "C" void kernel_launch(void* const* d_in, const int* in_sizes, int n_in,
                              void* d_out, int out_size, void* d_ws, size_t ws_size,
                              hipStream_t stream) {
  (void)in_sizes; (void)n_in; (void)out_size;
  const float* x    = (const float*)d_in[0];
  const float* in_w = (const float*)d_in[1];
  const float* in_b = (const float*)d_in[2];
  const float* ipw  = (const float*)d_in[3];
  const float* cw   = (const float*)d_in[4];
  const float* cb   = (const float*)d_in[5];
  const float* xpw  = (const float*)d_in[6];
  const float* dtw  = (const float*)d_in[7];
  const float* dtb  = (const float*)d_in[8];
  const float* Alog = (const float*)d_in[9];
  const float* Dp   = (const float*)d_in[10];
  const float* opw  = (const float*)d_in[11];
  const float* nw   = (const float*)d_in[12];
  const float* nbv  = (const float*)d_in[13];
  const float* clw  = (const float*)d_in[14];
  const float* clb  = (const float*)d_in[15];
  float* out = (float*)d_out;

  // adaptive batch chunking to fit workspace: per-token floats = 512+2048+1024+64+1024+1024
  const size_t per_m_bytes = 5696ull * 4ull;
  int nb = 16;
  while (nb > 1 && ((size_t)nb * L_SEQ * per_m_bytes + 16 * DM * 4) > ws_size) nb >>= 1;
  int Mc = nb * L_SEQ;

  char* p = (char*)d_ws;
  float* h      = (float*)p; p += (size_t)Mc * DM   * 4;
  float* xz     = (float*)p; p += (size_t)Mc * 2048 * 4;
  float* u      = (float*)p; p += (size_t)Mc * DI   * 4;
  float* dblb   = (float*)p; p += (size_t)Mc * 64   * 4;
  float* dtv    = (float*)p; p += (size_t)Mc * DI   * 4;
  float* y      = (float*)p; p += (size_t)Mc * DI   * 4;
  float* pooled = (float*)p;

  hipMemsetAsync(pooled, 0, 16 * DM * 4, stream);

  for (int b0 = 0; b0 < 16; b0 += nb) {
    embed_kernel<<<Mc * 2, 256, 0, stream>>>(x, in_w, in_b, h, b0, Mc);
    for (int layer = 0; layer < NLAYERS; ++layer) {
      const float* ipw_l  = ipw  + (size_t)layer * 2048 * DM;
      const float* cw_l   = cw   + (size_t)layer * DI * 4;
      const float* cb_l   = cb   + (size_t)layer * DI;
      const float* xpw_l  = xpw  + (size_t)layer * 64 * DI;
      const float* dtw_l  = dtw  + (size_t)layer * DI * 32;
      const float* dtb_l  = dtb  + (size_t)layer * DI;
      const float* Alog_l = Alog + (size_t)layer * DI * DSTATE;
      const float* Dp_l   = Dp   + (size_t)layer * DI;
      const float* opw_l  = opw  + (size_t)layer * DM * DI;

      gemm_split3<<<dim3(2048 / GBN, Mc / GBM), 256, 0, stream>>>(
          h, ipw_l, xz, Mc, 2048, DM, DM, DM, 2048);
      conv_silu_kernel<<<Mc * 4, 256, 0, stream>>>(xz, cw_l, cb_l, u, Mc);
      gemm_split3<<<dim3(64 / GBN, Mc / GBM), 256, 0, stream>>>(
          u, xpw_l, dblb, Mc, 64, DI, DI, DI, 64);
      dt_kernel<<<dim3(Mc / 64, 4), 256, 0, stream>>>(dblb, dtw_l, dtb_l, dtv, Mc);
      scan_kernel<<<nb * 16, 256, 0, stream>>>(dtv, u, xz, dblb, Alog_l, Dp_l, y);
      gemm_split3<<<dim3(DM / GBN, Mc / GBM), 256, 0, stream>>>(
          y, opw_l, h, Mc, DM, DI, DI, DI, DM);
    }
    pool_kernel<<<nb * 32, 512, 0, stream>>>(h, pooled, b0);
  }
  head_kernel<<<16, 512, 0, stream>>>(pooled, nw, nbv, clw, clb, out);
}

// Round 2
// 16308.354 us; speedup vs baseline: 3.2323x; 3.2323x over previous
//
#include <hip/hip_runtime.h>
#include <hip/hip_bf16.h>
#include <math.h>

#define L_SEQ 4096
#define DM 512
#define DI 1024
#define DSTATE 16
#define NLAYERS 4
#define NC 8          // scan chunks
#define LC 512        // chunk length (L_SEQ / NC)

typedef __bf16 v8bf __attribute__((ext_vector_type(8)));
typedef __bf16 v4bf __attribute__((ext_vector_type(4)));
typedef float  v4f  __attribute__((ext_vector_type(4)));

static __device__ __forceinline__ v4f mfma16(v8bf a, v8bf b, v4f c) {
  return __builtin_amdgcn_mfma_f32_16x16x32_bf16(a, b, c, 0, 0, 0);
}

// ---------------------------------------------------------------------------
// Embed: h[m][d] = in_b[d] + sum_c x[b][c][l] * in_w[d][c]
// ---------------------------------------------------------------------------
__global__ void embed_kernel(const float* __restrict__ x, const float* __restrict__ in_w,
                             const float* __restrict__ in_b, float* __restrict__ h,
                             int b0, int Mc) {
  int idx = blockIdx.x * 256 + threadIdx.x;   // over Mc*512
  int d = idx & (DM - 1);
  int m = idx >> 9;
  if (m >= Mc) return;
  int bg = b0 + (m >> 12);
  int l  = m & (L_SEQ - 1);
  const float* xp = x + ((size_t)bg * 3) * L_SEQ + l;
  float v = in_b[d] + xp[0] * in_w[d*3+0] + xp[L_SEQ] * in_w[d*3+1] + xp[2*L_SEQ] * in_w[d*3+2];
  h[(size_t)m * DM + d] = v;
}

// ---------------------------------------------------------------------------
// Split-bf16 3-pass MFMA GEMM: C[M][N] = A[M][K] * B[N][K]^T  (all fp32 in/out)
// ---------------------------------------------------------------------------
#define GBM 128
#define GBN 64
#define GBK 64
#define ROWB 272

__global__ __launch_bounds__(256) void gemm_split3(
    const float* __restrict__ A, const float* __restrict__ Bw, float* __restrict__ C,
    int M, int N, int K, int lda, int ldb, int ldc) {
  __shared__ __align__(16) char lds[GBM * ROWB + GBN * ROWB];
  char* aLds = lds;
  char* bLds = lds + GBM * ROWB;
  int tid  = threadIdx.x;
  int m0   = blockIdx.y * GBM;
  int n0   = blockIdx.x * GBN;
  int wave = tid >> 6, lane = tid & 63;
  int lrow = lane & 15, lq = lane >> 4;

  v4f acc[2][4];
#pragma unroll
  for (int i = 0; i < 2; ++i)
#pragma unroll
    for (int j = 0; j < 4; ++j)
#pragma unroll
      for (int e = 0; e < 4; ++e) acc[i][j][e] = 0.0f;

  int srow = tid >> 4;            // 0..15
  int scol = (tid & 15) * 4;      // float4 col within BK
  int kg   = scol >> 3;           // kgroup 0..7
  int ko   = scol & 7;            // 0 or 4

  for (int k0 = 0; k0 < K; k0 += GBK) {
    float4 av[8];
#pragma unroll
    for (int r = 0; r < 8; ++r)
      av[r] = *reinterpret_cast<const float4*>(A + (size_t)(m0 + srow + 16*r) * lda + k0 + scol);
    float4 bv[4];
#pragma unroll
    for (int r = 0; r < 4; ++r)
      bv[r] = *reinterpret_cast<const float4*>(Bw + (size_t)(n0 + srow + 16*r) * ldb + k0 + scol);

    __syncthreads();
#pragma unroll
    for (int r = 0; r < 8; ++r) {
      float4 v = av[r];
      char* p = aLds + (srow + 16*r) * ROWB + kg * 32 + ko * 2;
      v4bf hv, lv;
      hv[0]=(__bf16)v.x; hv[1]=(__bf16)v.y; hv[2]=(__bf16)v.z; hv[3]=(__bf16)v.w;
      lv[0]=(__bf16)(v.x-(float)hv[0]); lv[1]=(__bf16)(v.y-(float)hv[1]);
      lv[2]=(__bf16)(v.z-(float)hv[2]); lv[3]=(__bf16)(v.w-(float)hv[3]);
      *reinterpret_cast<v4bf*>(p)      = hv;
      *reinterpret_cast<v4bf*>(p + 16) = lv;
    }
#pragma unroll
    for (int r = 0; r < 4; ++r) {
      float4 v = bv[r];
      char* p = bLds + (srow + 16*r) * ROWB + kg * 32 + ko * 2;
      v4bf hv, lv;
      hv[0]=(__bf16)v.x; hv[1]=(__bf16)v.y; hv[2]=(__bf16)v.z; hv[3]=(__bf16)v.w;
      lv[0]=(__bf16)(v.x-(float)hv[0]); lv[1]=(__bf16)(v.y-(float)hv[1]);
      lv[2]=(__bf16)(v.z-(float)hv[2]); lv[3]=(__bf16)(v.w-(float)hv[3]);
      *reinterpret_cast<v4bf*>(p)      = hv;
      *reinterpret_cast<v4bf*>(p + 16) = lv;
    }
    __syncthreads();

#pragma unroll
    for (int kk = 0; kk < GBK / 32; ++kk) {
      v8bf aF[2][2], bF[4][2];
#pragma unroll
      for (int mt = 0; mt < 2; ++mt) {
        const char* p = aLds + (wave*32 + mt*16 + lrow) * ROWB + (kk*4 + lq) * 32;
        aF[mt][0] = *reinterpret_cast<const v8bf*>(p);
        aF[mt][1] = *reinterpret_cast<const v8bf*>(p + 16);
      }
#pragma unroll
      for (int nt = 0; nt < 4; ++nt) {
        const char* p = bLds + (nt*16 + lrow) * ROWB + (kk*4 + lq) * 32;
        bF[nt][0] = *reinterpret_cast<const v8bf*>(p);
        bF[nt][1] = *reinterpret_cast<const v8bf*>(p + 16);
      }
#pragma unroll
      for (int mt = 0; mt < 2; ++mt)
#pragma unroll
        for (int nt = 0; nt < 4; ++nt) {
          acc[mt][nt] = mfma16(aF[mt][0], bF[nt][0], acc[mt][nt]);  // hi*hi
          acc[mt][nt] = mfma16(aF[mt][0], bF[nt][1], acc[mt][nt]);  // hi*lo
          acc[mt][nt] = mfma16(aF[mt][1], bF[nt][0], acc[mt][nt]);  // lo*hi
        }
    }
  }

#pragma unroll
  for (int mt = 0; mt < 2; ++mt)
#pragma unroll
    for (int nt = 0; nt < 4; ++nt) {
      int rbase = m0 + wave*32 + mt*16 + lq*4;
      int cidx  = n0 + nt*16 + lrow;
#pragma unroll
      for (int r = 0; r < 4; ++r)
        C[(size_t)(rbase + r) * ldc + cidx] = acc[mt][nt][r];
    }
}

// ---------------------------------------------------------------------------
// Depthwise causal conv (k=4) + bias + SiLU.
// ---------------------------------------------------------------------------
__global__ void conv_silu_kernel(const float* __restrict__ xz, const float* __restrict__ cw,
                                 const float* __restrict__ cb, float* __restrict__ u, int Mc) {
  int idx = blockIdx.x * 256 + threadIdx.x;   // over Mc*DI
  int d = idx & (DI - 1);
  int m = idx >> 10;
  if (m >= Mc) return;
  int t = m & (L_SEQ - 1);
  float acc = cb[d];
#pragma unroll
  for (int k = 0; k < 4; ++k) {
    int tt = t - 3 + k;
    if (tt >= 0) acc += xz[(size_t)(m + k - 3) * 2048 + d] * cw[d*4 + k];
  }
  u[(size_t)m * DI + d] = acc / (1.0f + expf(-acc));
}

// ---------------------------------------------------------------------------
// dt tile kernel: dt[m][d] = softplus(dbl[m][0:32].dtw[d][:] + dtb[d])
// 64 tokens x 64 dims per block; thread = 4 tokens x 4 dims (dims strided 16).
// ---------------------------------------------------------------------------
__global__ __launch_bounds__(256) void dt_tile(const float* __restrict__ dbl,
                                               const float* __restrict__ dtw,
                                               const float* __restrict__ dtb,
                                               float* __restrict__ dt) {
  __shared__ float s_a[64][33];
  __shared__ float s_w[64][33];
  int tid = threadIdx.x;
  int m0 = blockIdx.x * 64, d0 = blockIdx.y * 64;
#pragma unroll
  for (int i = 0; i < 8; ++i) {
    int idx = tid + i * 256;
    int r = idx >> 5, cc = idx & 31;
    s_a[r][cc] = dbl[(size_t)(m0 + r) * 64 + cc];
    s_w[r][cc] = dtw[(size_t)(d0 + r) * 32 + cc];
  }
  __syncthreads();
  int tm = tid >> 4, td = tid & 15;
  float acc[4][4];
#pragma unroll
  for (int i = 0; i < 4; ++i)
#pragma unroll
    for (int j = 0; j < 4; ++j) acc[i][j] = dtb[d0 + td + 16 * j];
#pragma unroll
  for (int k = 0; k < 32; ++k) {
    float a_[4], w_[4];
#pragma unroll
    for (int i = 0; i < 4; ++i) a_[i] = s_a[tm * 4 + i][k];
#pragma unroll
    for (int j = 0; j < 4; ++j) w_[j] = s_w[td + 16 * j][k];
#pragma unroll
    for (int i = 0; i < 4; ++i)
#pragma unroll
      for (int j = 0; j < 4; ++j) acc[i][j] += a_[i] * w_[j];
  }
#pragma unroll
  for (int i = 0; i < 4; ++i)
#pragma unroll
    for (int j = 0; j < 4; ++j) {
      float v = acc[i][j];
      float sp = (v > 15.0f) ? v : log1pf(expf(v));
      dt[(size_t)(m0 + tm * 4 + i) * DI + d0 + td + 16 * j] = sp;
    }
}

// ---------------------------------------------------------------------------
// Scan pass 1: per chunk, from h=0 compute final state + running decay product.
// grid (16 dgroups, NC-1 chunks, nb batch); 4 lanes per (b,d), 4 states each.
// ---------------------------------------------------------------------------
#define TT 16
__global__ __launch_bounds__(256) void scan_pass1(
    const float* __restrict__ dt, const float* __restrict__ u,
    const float* __restrict__ dbl, const float* __restrict__ Alog,
    float* __restrict__ cfF, float* __restrict__ cfP) {
  __shared__ __align__(16) float s_dt[TT][64];
  __shared__ __align__(16) float s_u [TT][64];
  __shared__ __align__(16) float s_b [TT][16];
  int tid = threadIdx.x;
  int d0 = blockIdx.x * 64;
  int c  = blockIdx.y;
  int bi = blockIdx.z;
  int dl = tid >> 2;
  int sg = (tid & 3) * 4;
  int d  = d0 + dl;
  float a2[4], h[4] = {0.f,0.f,0.f,0.f}, p[4] = {1.f,1.f,1.f,1.f};
#pragma unroll
  for (int j = 0; j < 4; ++j)
    a2[j] = -expf(Alog[(size_t)d * DSTATE + sg + j]) * 1.44269504088896340736f;
  size_t mbase = (size_t)bi * L_SEQ + (size_t)c * LC;
  int tr = tid >> 4, c4 = (tid & 15) * 4;

  for (int t0 = 0; t0 < LC; t0 += TT) {
    size_t m = mbase + t0 + tr;
    *reinterpret_cast<float4*>(&s_dt[tr][c4]) = *reinterpret_cast<const float4*>(dt + m*DI + d0 + c4);
    *reinterpret_cast<float4*>(&s_u [tr][c4]) = *reinterpret_cast<const float4*>(u  + m*DI + d0 + c4);
    if (tid < 64) {
      int tr3 = tid >> 2, cB = (tid & 3) * 4;
      *reinterpret_cast<float4*>(&s_b[tr3][cB]) =
          *reinterpret_cast<const float4*>(dbl + (mbase + t0 + tr3)*64 + 32 + cB);
    }
    __syncthreads();
#pragma unroll
    for (int t = 0; t < TT; ++t) {
      float dtv = s_dt[t][dl];
      float cu  = dtv * s_u[t][dl];
      float4 Bv = *reinterpret_cast<const float4*>(&s_b[t][sg]);
      float dA;
      dA = exp2f(dtv * a2[0]); h[0] = dA*h[0] + cu*Bv.x; p[0] *= dA;
      dA = exp2f(dtv * a2[1]); h[1] = dA*h[1] + cu*Bv.y; p[1] *= dA;
      dA = exp2f(dtv * a2[2]); h[2] = dA*h[2] + cu*Bv.z; p[2] *= dA;
      dA = exp2f(dtv * a2[3]); h[3] = dA*h[3] + cu*Bv.w; p[3] *= dA;
    }
    __syncthreads();
  }
  size_t cbase = (((size_t)bi * NC + c) * DI + d) * DSTATE + sg;
  *reinterpret_cast<float4*>(cfF + cbase) = make_float4(h[0],h[1],h[2],h[3]);
  *reinterpret_cast<float4*>(cfP + cbase) = make_float4(p[0],p[1],p[2],p[3]);
}

// ---------------------------------------------------------------------------
// Scan pass 2: serial prefix over chunks, in-place (final -> entry states).
// one thread per (b,d).
// ---------------------------------------------------------------------------
__global__ __launch_bounds__(256) void chunk_prefix(float* __restrict__ cfF,
                                                    const float* __restrict__ cfP,
                                                    int nb) {
  int gid = blockIdx.x * 256 + threadIdx.x;
  if (gid >= nb * DI) return;
  int bi = gid >> 10;
  int d  = gid & (DI - 1);
  float4 carry[4];
#pragma unroll
  for (int q = 0; q < 4; ++q) carry[q] = make_float4(0.f,0.f,0.f,0.f);
  size_t base = (((size_t)bi * NC) * DI + d) * DSTATE;
  const size_t cs = (size_t)DI * DSTATE;
  for (int c = 0; c < NC; ++c) {
    float4 f[4], p[4];
    if (c < NC - 1) {
#pragma unroll
      for (int q = 0; q < 4; ++q) {
        f[q] = *reinterpret_cast<const float4*>(cfF + base + c*cs + q*4);
        p[q] = *reinterpret_cast<const float4*>(cfP + base + c*cs + q*4);
      }
    }
#pragma unroll
    for (int q = 0; q < 4; ++q)
      *reinterpret_cast<float4*>(cfF + base + c*cs + q*4) = carry[q];
    if (c < NC - 1) {
#pragma unroll
      for (int q = 0; q < 4; ++q) {
        carry[q].x = p[q].x*carry[q].x + f[q].x;
        carry[q].y = p[q].y*carry[q].y + f[q].y;
        carry[q].z = p[q].z*carry[q].z + f[q].z;
        carry[q].w = p[q].w*carry[q].w + f[q].w;
      }
    }
  }
}

// ---------------------------------------------------------------------------
// Scan pass 3: full scan per chunk from entry state + gate + y write.
// grid (16 dgroups, NC chunks, nb batch)
// ---------------------------------------------------------------------------
__global__ __launch_bounds__(256) void scan_pass3(
    const float* __restrict__ dt, const float* __restrict__ u,
    const float* __restrict__ xz, const float* __restrict__ dbl,
    const float* __restrict__ Alog, const float* __restrict__ Dp,
    const float* __restrict__ cfF, float* __restrict__ y) {
  __shared__ __align__(16) float s_dt[TT][64];
  __shared__ __align__(16) float s_u [TT][64];
  __shared__ __align__(16) float s_z [TT][64];
  __shared__ __align__(16) float s_bc[TT][32];
  __shared__ __align__(16) float s_y [TT][64];
  int tid = threadIdx.x;
  int d0 = blockIdx.x * 64;
  int c  = blockIdx.y;
  int bi = blockIdx.z;
  int dl = tid >> 2;
  int sg = (tid & 3) * 4;
  int d  = d0 + dl;
  float a2[4], hst[4];
  size_t cbase = (((size_t)bi * NC + c) * DI + d) * DSTATE + sg;
  float4 ent = *reinterpret_cast<const float4*>(cfF + cbase);
  hst[0]=ent.x; hst[1]=ent.y; hst[2]=ent.z; hst[3]=ent.w;
#pragma unroll
  for (int j = 0; j < 4; ++j)
    a2[j] = -expf(Alog[(size_t)d * DSTATE + sg + j]) * 1.44269504088896340736f;
  float dp = Dp[d];
  size_t mbase = (size_t)bi * L_SEQ + (size_t)c * LC;

  int tr = tid >> 4, c4 = (tid & 15) * 4;
  int tr2 = tid >> 3, c2 = (tid & 7) * 4;

  for (int t0 = 0; t0 < LC; t0 += TT) {
    size_t m = mbase + t0 + tr;
    *reinterpret_cast<float4*>(&s_dt[tr][c4]) = *reinterpret_cast<const float4*>(dt + m*DI + d0 + c4);
    *reinterpret_cast<float4*>(&s_u [tr][c4]) = *reinterpret_cast<const float4*>(u  + m*DI + d0 + c4);
    *reinterpret_cast<float4*>(&s_z [tr][c4]) = *reinterpret_cast<const float4*>(xz + m*2048 + DI + d0 + c4);
    if (tid < 128) {
      size_t m2 = mbase + t0 + tr2;
      *reinterpret_cast<float4*>(&s_bc[tr2][c2]) = *reinterpret_cast<const float4*>(dbl + m2*64 + 32 + c2);
    }
    __syncthreads();
#pragma unroll
    for (int t = 0; t < TT; ++t) {
      float dtv = s_dt[t][dl];
      float uv  = s_u[t][dl];
      float cu  = dtv * uv;
      float4 Bv = *reinterpret_cast<const float4*>(&s_bc[t][sg]);
      float4 Cv = *reinterpret_cast<const float4*>(&s_bc[t][16 + sg]);
      float yp = 0.0f;
      {
        float dA;
        dA = exp2f(dtv * a2[0]); hst[0] = dA*hst[0] + cu*Bv.x; yp += hst[0]*Cv.x;
        dA = exp2f(dtv * a2[1]); hst[1] = dA*hst[1] + cu*Bv.y; yp += hst[1]*Cv.y;
        dA = exp2f(dtv * a2[2]); hst[2] = dA*hst[2] + cu*Bv.z; yp += hst[2]*Cv.z;
        dA = exp2f(dtv * a2[3]); hst[3] = dA*hst[3] + cu*Bv.w; yp += hst[3]*Cv.w;
      }
      yp += __shfl_xor(yp, 1);
      yp += __shfl_xor(yp, 2);
      if ((tid & 3) == 0) {
        float zv = s_z[t][dl];
        s_y[t][dl] = (yp + uv * dp) * (zv / (1.0f + expf(-zv)));
      }
    }
    __syncthreads();
    *reinterpret_cast<float4*>(y + m*DI + d0 + c4) = *reinterpret_cast<float4*>(&s_y[tr][c4]);
    __syncthreads();
  }
}

// ---------------------------------------------------------------------------
// Pool
// ---------------------------------------------------------------------------
__global__ __launch_bounds__(512) void pool_kernel(const float* __restrict__ h,
                                                   float* __restrict__ pooled,
                                                   int b0) {
  int b = blockIdx.x >> 5;
  int chunk = blockIdx.x & 31;
  int d = threadIdx.x;
  float s = 0.0f;
  size_t base = (size_t)b * L_SEQ + chunk * 128;
  for (int l = 0; l < 128; ++l) s += h[(base + l) * DM + d];
  atomicAdd(pooled + (size_t)(b0 + b) * DM + d, s * (1.0f / 4096.0f));
}

// ---------------------------------------------------------------------------
// Head
// ---------------------------------------------------------------------------
__global__ __launch_bounds__(512) void head_kernel(const float* __restrict__ pooled,
                                                   const float* __restrict__ nw,
                                                   const float* __restrict__ nbv,
                                                   const float* __restrict__ clw,
                                                   const float* __restrict__ clb,
                                                   float* __restrict__ out) {
  __shared__ float rs[8], rq[8];
  __shared__ float ln[512];
  int b = blockIdx.x, tid = threadIdx.x;
  int wid = tid >> 6, lane = tid & 63;
  float v = pooled[(size_t)b * DM + tid];
  float s = v, q = v * v;
#pragma unroll
  for (int off = 1; off < 64; off <<= 1) { s += __shfl_xor(s, off); q += __shfl_xor(q, off); }
  if (lane == 0) { rs[wid] = s; rq[wid] = q; }
  __syncthreads();
  if (tid == 0) {
    float S = 0, Q = 0;
    for (int i = 0; i < 8; ++i) { S += rs[i]; Q += rq[i]; }
    rs[0] = S; rq[0] = Q;
  }
  __syncthreads();
  float mu  = rs[0] / 512.0f;
  float var = rq[0] / 512.0f - mu * mu;
  ln[tid] = (v - mu) * rsqrtf(var + 1e-5f) * nw[tid] + nbv[tid];
  __syncthreads();
  if (tid < 320) {
    int c = tid >> 5, l2 = tid & 31;
    float p = 0.0f;
    for (int dd = l2; dd < 512; dd += 32) p += ln[dd] * clw[c * 512 + dd];
#pragma unroll
    for (int off = 1; off < 32; off <<= 1) p += __shfl_xor(p, off);
    if (l2 == 0) out[(size_t)b * 10 + c] = p + clb[c];
  }
}

// ---------------------------------------------------------------------------
extern "C" void kernel_launch(void* const* d_in, const int* in_sizes, int n_in,
                              void* d_out, int out_size, void* d_ws, size_t ws_size,
                              hipStream_t stream) {
  (void)in_sizes; (void)n_in; (void)out_size;
  const float* x    = (const float*)d_in[0];
  const float* in_w = (const float*)d_in[1];
  const float* in_b = (const float*)d_in[2];
  const float* ipw  = (const float*)d_in[3];
  const float* cw   = (const float*)d_in[4];
  const float* cb   = (const float*)d_in[5];
  const float* xpw  = (const float*)d_in[6];
  const float* dtw  = (const float*)d_in[7];
  const float* dtb  = (const float*)d_in[8];
  const float* Alog = (const float*)d_in[9];
  const float* Dp   = (const float*)d_in[10];
  const float* opw  = (const float*)d_in[11];
  const float* nw   = (const float*)d_in[12];
  const float* nbv  = (const float*)d_in[13];
  const float* clw  = (const float*)d_in[14];
  const float* clb  = (const float*)d_in[15];
  float* out = (float*)d_out;

  // per-token floats = h 512 + xz 2048 + u 1024 + dbl 64 + dt 1024 + y 1024 = 5696
  const size_t per_m_bytes = 5696ull * 4ull;
  const size_t cf_per_b    = 2ull * NC * DI * DSTATE * 4ull;  // cfF + cfP
  int nb = 16;
  while (nb > 1 && ((size_t)nb * L_SEQ * per_m_bytes + (size_t)nb * cf_per_b + 16 * DM * 4) > ws_size)
    nb >>= 1;
  int Mc = nb * L_SEQ;

  char* p = (char*)d_ws;
  float* h      = (float*)p; p += (size_t)Mc * DM   * 4;
  float* xz     = (float*)p; p += (size_t)Mc * 2048 * 4;
  float* u      = (float*)p; p += (size_t)Mc * DI   * 4;
  float* dblb   = (float*)p; p += (size_t)Mc * 64   * 4;
  float* dtv    = (float*)p; p += (size_t)Mc * DI   * 4;
  float* y      = (float*)p; p += (size_t)Mc * DI   * 4;
  float* cfF    = (float*)p; p += (size_t)nb * NC * DI * DSTATE * 4;
  float* cfP    = (float*)p; p += (size_t)nb * NC * DI * DSTATE * 4;
  float* pooled = (float*)p;

  hipMemsetAsync(pooled, 0, 16 * DM * 4, stream);

  for (int b0 = 0; b0 < 16; b0 += nb) {
    embed_kernel<<<Mc * 2, 256, 0, stream>>>(x, in_w, in_b, h, b0, Mc);
    for (int layer = 0; layer < NLAYERS; ++layer) {
      const float* ipw_l  = ipw  + (size_t)layer * 2048 * DM;
      const float* cw_l   = cw   + (size_t)layer * DI * 4;
      const float* cb_l   = cb   + (size_t)layer * DI;
      const float* xpw_l  = xpw  + (size_t)layer * 64 * DI;
      const float* dtw_l  = dtw  + (size_t)layer * DI * 32;
      const float* dtb_l  = dtb  + (size_t)layer * DI;
      const float* Alog_l = Alog + (size_t)layer * DI * DSTATE;
      const float* Dp_l   = Dp   + (size_t)layer * DI;
      const float* opw_l  = opw  + (size_t)layer * DM * DI;

      gemm_split3<<<dim3(2048 / GBN, Mc / GBM), 256, 0, stream>>>(
          h, ipw_l, xz, Mc, 2048, DM, DM, DM, 2048);
      conv_silu_kernel<<<Mc * 4, 256, 0, stream>>>(xz, cw_l, cb_l, u, Mc);
      gemm_split3<<<dim3(64 / GBN, Mc / GBM), 256, 0, stream>>>(
          u, xpw_l, dblb, Mc, 64, DI, DI, DI, 64);
      dt_tile<<<dim3(Mc / 64, 16), 256, 0, stream>>>(dblb, dtw_l, dtb_l, dtv);
      scan_pass1<<<dim3(16, NC - 1, nb), 256, 0, stream>>>(dtv, u, dblb, Alog_l, cfF, cfP);
      chunk_prefix<<<(nb * DI + 255) / 256, 256, 0, stream>>>(cfF, cfP, nb);
      scan_pass3<<<dim3(16, NC, nb), 256, 0, stream>>>(dtv, u, xz, dblb, Alog_l, Dp_l, cfF, y);
      gemm_split3<<<dim3(DM / GBN, Mc / GBM), 256, 0, stream>>>(
          y, opw_l, h, Mc, DM, DI, DI, DI, DM);
    }
    pool_kernel<<<nb * 32, 512, 0, stream>>>(h, pooled, b0);
  }
  head_kernel<<<16, 512, 0, stream>>>(pooled, nw, nbv, clw, clb, out);
}